// Round 13
// baseline (520.099 us; speedup 1.0000x reference)
//
#include <hip/hip_runtime.h>

// FirNeXtV2: DDSP-style synth. B=4, NF=512 frames, BLK=512 hop, L=262144.
// Model (r1-r12 quadrature forensics): ref = f32 pipeline whose cumsum was
// lowered via XLA's ReduceWindowRewriter: chunked scan, base_length=16,
// sequential within chunk, recursive carry scan, one rounded add per level.
// Eval f32 (accurate libm), convs f32.

#define BLKS  512
#define WL    2048
#define W4    512
#define NB    4
#define NFR   512
#define LTOT  (NFR*BLKS)     // 262144
#define SSTRIDE (2*LTOT)
#define SN_LEN 260096        // WL*127

// ---------------------------------------------------------------------------
// Kernel 1: XLA ReduceWindowRewriter-style chunked f32 cumsum (base 16).
// Levels: 262144 -> 16384 -> 1024 -> 64 -> 4 (direct). Within each chunk of
// 16: strictly sequential f32 prefix (the RW base case reduces the window
// left-to-right). Combine top-down: elem += carry(level+1)[chunk-1] — one
// rounded f32 add per level, matching the recursive rewrite's value nesting.
// ---------------------------------------------------------------------------
__global__ void __launch_bounds__(1024) k_scan(const float* __restrict__ f0_frames,
                                               float* __restrict__ sb) {
    int b = blockIdx.x;
    float* L0 = sb + (size_t)b * SSTRIDE;   // 262144
    float* L1 = L0 + LTOT;                  // 16384
    float* L2 = L1 + 16384;                 // 1024
    float* L3 = L2 + 1024;                  // 64
    float* L4 = L3 + 64;                    // 4
    int tid = threadIdx.x;
    for (int t = tid; t < LTOT; t += 1024)
        L0[t] = f0_frames[b*NFR + (t >> 9)] / 44100.0f;   // f32 div, = jnp f0/SR
    __syncthreads();
    // level-0 within-chunk sequential prefixes + chunk sums
    for (int c = tid; c < LTOT/16; c += 1024) {
        float acc = 0.0f;
        #pragma unroll
        for (int j = 0; j < 16; ++j) { acc = acc + L0[c*16 + j]; L0[c*16 + j] = acc; }
        L1[c] = acc;
    }
    __syncthreads();
    for (int c = tid; c < 16384/16; c += 1024) {
        float acc = 0.0f;
        #pragma unroll
        for (int j = 0; j < 16; ++j) { acc = acc + L1[c*16 + j]; L1[c*16 + j] = acc; }
        L2[c] = acc;
    }
    __syncthreads();
    for (int c = tid; c < 1024/16; c += 1024) {
        float acc = 0.0f;
        #pragma unroll
        for (int j = 0; j < 16; ++j) { acc = acc + L2[c*16 + j]; L2[c*16 + j] = acc; }
        L3[c] = acc;
    }
    __syncthreads();
    for (int c = tid; c < 4; c += 1024) {
        float acc = 0.0f;
        #pragma unroll
        for (int j = 0; j < 16; ++j) { acc = acc + L3[c*16 + j]; L3[c*16 + j] = acc; }
        L4[c] = acc;
    }
    __syncthreads();
    if (tid == 0) {                          // level 4: n=4 <= base, direct scan
        float acc = 0.0f;
        #pragma unroll
        for (int j = 0; j < 4; ++j) { acc = acc + L4[j]; L4[j] = acc; }
    }
    __syncthreads();
    // combine top-down (each level finalized before the one below uses it)
    for (int i = tid; i < 64; i += 1024)
        if (i >= 16) L3[i] = L3[i] + L4[i/16 - 1];
    __syncthreads();
    for (int i = tid; i < 1024; i += 1024)
        if (i >= 16) L2[i] = L2[i] + L3[i/16 - 1];
    __syncthreads();
    for (int i = tid; i < 16384; i += 1024)
        if (i >= 16) L1[i] = L1[i] + L2[i/16 - 1];
    __syncthreads();
    for (int i = tid; i < LTOT; i += 1024)
        if (i >= 16) L0[i] = L0[i] + L1[i/16 - 1];
    // L0[0..LTOT) = chunked-scan f32 inclusive prefix sums.
}

// ---------------------------------------------------------------------------
// Kernel 2: harmonic source, float32, JAX/numpy op order, ocml sinf.
// ---------------------------------------------------------------------------
__global__ void __launch_bounds__(256) k_source(const float* __restrict__ f0_frames,
                                                const float* __restrict__ sb,
                                                float* __restrict__ hs) {
    int F = blockIdx.x, b = blockIdx.y;
    int tid = threadIdx.x;
    float f0 = f0_frames[b*NFR + F];
    float af = rintf(44100.0f / fmaxf(f0, 20.0f) * 0.5f) * 2.0f + 1.0f;
    const float PIF = 3.14159274101257324f;   // float32(np.pi)
    for (int i = tid; i < BLKS; i += 256) {
        float c = sb[(size_t)b*SSTRIDE + F*BLKS + i];
        float x = c - floorf(c);
        float pix = PIF * x;
        float v;
        if (pix < 1e-8f) v = 1.0f;
        else             v = sinf(af * pix) / (af * sinf(pix));
        hs[(size_t)(b*NFR + F)*BLKS + i] = v;
    }
}

// ---------------------------------------------------------------------------
// Kernel 3: mix[t] = sum_{s=t-512}^{t-1} hks[f(s)][s-t+512]*hs[s]
//                  +                      nk[f(s)][s-t+512]*noise[s]
// ---------------------------------------------------------------------------
__global__ void __launch_bounds__(512) k_mix(const float* __restrict__ hs,
                                             const float* __restrict__ sn,
                                             const float* __restrict__ hks,
                                             const float* __restrict__ nk,
                                             float* __restrict__ mixg) {
    __shared__ float sHs[2*BLKS];
    __shared__ float sNz[2*BLKS];
    int F = blockIdx.x, b = blockIdx.y;
    int tid = threadIdx.x;
    int s0 = (F - 1) * BLKS;
    for (int i = tid; i < 2*BLKS; i += 512) {
        int s = s0 + i;
        float hv = 0.0f, nv = 0.0f;
        if (s >= 0 && s < LTOT) {
            hv = hs[(size_t)b*LTOT + s];
            nv = sn[s % SN_LEN] * 0.3162f;     // tiled static noise
        }
        sHs[i] = hv; sNz[i] = nv;
    }
    __syncthreads();
    int j = tid;                               // output t = 512F + j
    const float* khF = hks + (size_t)(b*NFR + F)*W4;
    const float* knF = nk  + (size_t)(b*NFR + F)*W4;
    float acc = 0.0f;
    int base = W4 - j;
    #pragma unroll 4
    for (int m = 0; m < j; ++m)
        acc += khF[base + m] * sHs[BLKS + m] + knF[base + m] * sNz[BLKS + m];
    if (F > 0) {
        const float* khP = khF - W4;
        const float* knP = knF - W4;
        int lim = W4 - j;
        #pragma unroll 4
        for (int k = 0; k < lim; ++k)
            acc += khP[k] * sHs[j + k] + knP[k] * sNz[j + k];
    }
    mixg[(size_t)b*LTOT + F*BLKS + j] = acc;
}

// ---------------------------------------------------------------------------
// Kernel 4: out[t] = clip( sum_{s=t-2048}^{t-1} hk[f(s)][s-t+2048]*mix[s] )
// ---------------------------------------------------------------------------
__global__ void __launch_bounds__(512) k_out(const float* __restrict__ mixg,
                                             const float* __restrict__ hk,
                                             float* __restrict__ outp) {
    __shared__ float sMix[5*BLKS];   // 10 KB
    int F = blockIdx.x, b = blockIdx.y;
    int tid = threadIdx.x;
    int s0 = (F - 4) * BLKS;
    for (int i = tid; i < 5*BLKS; i += 512) {
        int s = s0 + i;
        sMix[i] = (s >= 0) ? mixg[(size_t)b*LTOT + s] : 0.0f;
    }
    __syncthreads();
    int jm = tid;                    // output t = 512F + jm
    float acc = 0.0f;
    for (int q = 1; q <= 3; ++q) {
        int fs = F - 4 + q;
        if (fs < 0) continue;        // uniform per block
        const float* hkf = hk + (size_t)(b*NFR + fs)*WL;
        const float* sm  = sMix + BLKS*q;
        int kb = BLKS*q - jm;
        #pragma unroll 4
        for (int m = 0; m < BLKS; ++m)
            acc += hkf[kb + m] * sm[m];
    }
    const float* hkB = hk + (size_t)(b*NFR + F)*WL;
    #pragma unroll 4
    for (int m = 0; m < jm; ++m)
        acc += hkB[m + WL - jm] * sMix[4*BLKS + m];
    if (F >= 4) {
        const float* hkA = hk + (size_t)(b*NFR + F - 4)*WL;
        #pragma unroll 4
        for (int m = jm; m < BLKS; ++m)
            acc += hkA[m - jm] * sMix[m];
    }
    float r = fminf(fmaxf(acc, -1.0f), 1.0f);
    outp[(size_t)b*LTOT + F*BLKS + jm] = r;
}

// ---------------------------------------------------------------------------
extern "C" void kernel_launch(void* const* d_in, const int* in_sizes, int n_in,
                              void* d_out, int out_size, void* d_ws, size_t ws_size,
                              hipStream_t stream) {
    const float* f0  = (const float*)d_in[0];   // (B,NF,1)
    const float* hk  = (const float*)d_in[1];   // (B,NF,2048)
    const float* hks = (const float*)d_in[2];   // (B,NF,512)
    const float* nk  = (const float*)d_in[3];   // (B,NF,512)
    const float* sn  = (const float*)d_in[4];   // (260096,)
    float* outp = (float*)d_out;                // (B,L) f32

    float* ws   = (float*)d_ws;
    float* sb   = ws;                            // NB * 2L floats = 8 MB
    float* hsb  = ws + (size_t)NB*SSTRIDE;       // B*L f32 = 4 MB
    float* mixg = ws;                            // alias scan buffer (dead after k_source)
    // ws bytes needed: 12 MB

    hipLaunchKernelGGL(k_scan,   dim3(NB),      dim3(1024), 0, stream, f0, sb);
    hipLaunchKernelGGL(k_source, dim3(NFR, NB), dim3(256),  0, stream, f0, sb, hsb);
    hipLaunchKernelGGL(k_mix,    dim3(NFR, NB), dim3(512),  0, stream, hsb, sn, hks, nk, mixg);
    hipLaunchKernelGGL(k_out,    dim3(NFR, NB), dim3(512),  0, stream, mixg, hk, outp);
}